// Round 2
// baseline (1355.516 us; speedup 1.0000x reference)
//
#include <hip/hip_runtime.h>
#include <cstdint>
#include <cstddef>

typedef float  f32x4  __attribute__((ext_vector_type(4)));
typedef __bf16 bf16x8 __attribute__((ext_vector_type(8)));

// LDS aperture: low 32 bits of a flat shared pointer are the LDS offset.
#define AS1CV(p) ((const __attribute__((address_space(1))) void*)(uintptr_t)(p))
#define AS3V(p)  ((__attribute__((address_space(3))) void*)(uintptr_t)(p))

// ---------------------------------------------------------------------------
// fp32 -> bf16 convert (x). grid-stride free, exact-fit launch.
// ---------------------------------------------------------------------------
__global__ __launch_bounds__(256) void convert_k(
    const float* __restrict__ in, __bf16* __restrict__ out, long n)
{
  const long i = ((long)blockIdx.x * 256 + threadIdx.x) * 4;
  if (i + 3 < n) {
    float4 v = *(const float4*)(in + i);
    __bf16 e[4] = { (__bf16)v.x, (__bf16)v.y, (__bf16)v.z, (__bf16)v.w };
    *(uint2*)(out + i) = *(const uint2*)e;
  }
}

// ---------------------------------------------------------------------------
// Weight transpose + convert: out_bf16[c][r] = (bf16)in_f32[r][c].
// grid = (C/64, R/64), 256 threads.
// ---------------------------------------------------------------------------
__global__ __launch_bounds__(256) void transpose_f32_bf16_k(
    const float* __restrict__ in, __bf16* __restrict__ out, long inRow, long outRow)
{
  const long tr = (long)blockIdx.y * 64;
  const long tc = (long)blockIdx.x * 64;
  __shared__ float tile[64][65];
  const int tid = threadIdx.x;
  const int rr = tid >> 4, c4 = (tid & 15) * 4;
#pragma unroll
  for (int p = 0; p < 4; p++) {
    const int r = p * 16 + rr;
    float4 v = *(const float4*)(in + (tr + r) * inRow + tc + c4);  // coalesced 16B
    tile[r][c4]     = v.x;
    tile[r][c4 + 1] = v.y;
    tile[r][c4 + 2] = v.z;
    tile[r][c4 + 3] = v.w;
  }
  __syncthreads();
#pragma unroll
  for (int p = 0; p < 2; p++) {
    const int u  = p * 256 + tid;
    const int oc = u >> 3, ch = (u & 7) * 8;   // banks: (ch+oc+j)%32 -> 2-way, free
    unsigned short e[8];
#pragma unroll
    for (int j = 0; j < 8; j++) {
      __bf16 b = (__bf16)tile[ch + j][oc];
      e[j] = *(unsigned short*)&b;
    }
    *(uint4*)(out + (tc + oc) * outRow + tr + ch) = *(const uint4*)e;  // coalesced 16B
  }
}

// ---------------------------------------------------------------------------
// bf16 transpose with slices (for V relayout): out[c][r] = in[r][c].
// grid = (C/64, R/64, slices)
// ---------------------------------------------------------------------------
__global__ __launch_bounds__(256) void transpose_bf16_k(
    const __bf16* __restrict__ in, __bf16* __restrict__ out,
    long inRow, long outRow,
    int sliceDiv, long sliceOuter, long sliceInner, long outSlice)
{
  const int s = blockIdx.z;
  const __bf16* ip = in + (long)(s / sliceDiv) * sliceOuter + (long)(s % sliceDiv) * sliceInner;
  __bf16* op = out + (long)s * outSlice;
  const long tr = (long)blockIdx.y * 64;
  const long tc = (long)blockIdx.x * 64;
  __shared__ unsigned short tile[64][66];
  const int tid = threadIdx.x;
  const int rr  = tid >> 3;        // 0..31
  const int c8  = (tid & 7) * 8;   // 0..56
#pragma unroll
  for (int p = 0; p < 2; p++) {
    const int r = p * 32 + rr;
    uint4 v = *(const uint4*)(ip + (tr + r) * inRow + tc + c8);   // 8 bf16, 16B
    const unsigned short* e = (const unsigned short*)&v;
#pragma unroll
    for (int j = 0; j < 8; j++) tile[r][c8 + j] = e[j];
  }
  __syncthreads();
#pragma unroll
  for (int p = 0; p < 2; p++) {
    const int c = p * 32 + rr;
    unsigned short e[8];
#pragma unroll
    for (int j = 0; j < 8; j++) e[j] = tile[c8 + j][c];
    *(uint4*)(op + (tc + c) * outRow + tr + c8) = *(const uint4*)e;
  }
}

// ---------------------------------------------------------------------------
// m97-style GEMM: C[M][N] = A[M][K] * BT[N][K]^T, bf16 in, fp32 accum,
// OutT out. 128x128 tile, BK=32, 256 threads, 16x16x32 MFMA.
// grid = (N/128, M/128)
// ---------------------------------------------------------------------------
template <typename OutT>
__global__ __launch_bounds__(256) void gemm_bt(
    const __bf16* __restrict__ A, const __bf16* __restrict__ BT,
    OutT* __restrict__ C, int M, int N, int K)
{
  const int n0   = blockIdx.x * 128;
  const int m0   = blockIdx.y * 128;
  const int tid  = threadIdx.x;
  const int lane = tid & 63;
  const int wave = tid >> 6;
  const int quad = lane >> 4;
  const int r    = lane & 15;
  const int wm   = wave >> 1, wn = wave & 1;
  __shared__ __bf16 a_sm[128 * 32];
  __shared__ __bf16 b_sm[128 * 32];
  f32x4 acc[4][4] = {};
  const int rowLd = lane >> 2;          // 16 rows per wave-load
  const int chLd  = (lane & 3) * 8;     // 4 x 16B chunks per 64B row
  for (int k0 = 0; k0 < K; k0 += 32) {
    __syncthreads();
#pragma unroll
    for (int i = 0; i < 2; i++) {
      const int li = wave * 2 + i;
      const __bf16* ga = A  + (size_t)(m0 + li * 16 + rowLd) * K + k0 + chLd;
      __builtin_amdgcn_global_load_lds(AS1CV(ga), AS3V(a_sm + li * 512), 16, 0, 0);
      const __bf16* gb = BT + (size_t)(n0 + li * 16 + rowLd) * K + k0 + chLd;
      __builtin_amdgcn_global_load_lds(AS1CV(gb), AS3V(b_sm + li * 512), 16, 0, 0);
    }
    __syncthreads();
    bf16x8 af[4], bfr[4];
#pragma unroll
    for (int mi = 0; mi < 4; mi++)
      af[mi] = *(const bf16x8*)(a_sm + (wm * 64 + mi * 16 + r) * 32 + quad * 8);
#pragma unroll
    for (int ni = 0; ni < 4; ni++)
      bfr[ni] = *(const bf16x8*)(b_sm + (wn * 64 + ni * 16 + r) * 32 + quad * 8);
#pragma unroll
    for (int mi = 0; mi < 4; mi++)
#pragma unroll
      for (int ni = 0; ni < 4; ni++)
        acc[mi][ni] = __builtin_amdgcn_mfma_f32_16x16x32_bf16(af[mi], bfr[ni], acc[mi][ni], 0, 0, 0);
  }
  // C/D layout: col = lane&15, row = quad*4 + reg  (m89/m91-verified)
#pragma unroll
  for (int mi = 0; mi < 4; mi++)
#pragma unroll
    for (int ni = 0; ni < 4; ni++) {
      const int col = n0 + wn * 64 + ni * 16 + r;
#pragma unroll
      for (int g = 0; g < 4; g++) {
        const int row = m0 + wm * 64 + mi * 16 + quad * 4 + g;
        C[(size_t)row * N + col] = (OutT)acc[mi][ni][g];
      }
    }
}

// ---------------------------------------------------------------------------
// RoPE + relayout: qkv[B*T][6144](bf16) -> qr[B][H][T][D], kr[B][KV][T][D]
// grid = B*T, 256 threads. fp32 trig (np reference is fp32).
// ---------------------------------------------------------------------------
__global__ __launch_bounds__(256) void rope_k(
    const __bf16* __restrict__ qkv, __bf16* __restrict__ qr, __bf16* __restrict__ kr)
{
  const int m = blockIdx.x;      // 0..4095
  const int b = m >> 11;
  const int t = m & 2047;
  const __bf16* rowp = qkv + (size_t)m * 6144;
  for (int n = threadIdx.x; n < 5120; n += 256) {
    const bool isq  = n < 4096;
    const int local = isq ? n : (n - 4096);
    const int head  = local >> 7;
    const int d     = local & 127;
    const int j     = d & 63;
    const float ex   = (float)(2 * j) / 128.0f;
    const float invf = 1.0f / powf(10000.0f, ex);
    const float ang  = ((float)t * invf) * 2.0f;   // * B=2 per reference quirk
    const float c = cosf(ang), s = sinf(ang);
    const float v0 = (float)rowp[n];
    const float v1 = (float)rowp[n + ((d < 64) ? 64 : -64)];
    const float o  = (d < 64) ? (v0 * c - v1 * s) : (v0 * c + v1 * s);
    if (isq) qr[((size_t)(b * 32 + head) * 2048 + t) * 128 + d] = (__bf16)o;
    else     kr[((size_t)(b * 8  + head) * 2048 + t) * 128 + d] = (__bf16)o;
  }
}

// ---------------------------------------------------------------------------
// Flash attention, causal, GQA (4 q-heads per kv head), online softmax.
// qr[B][H][T][D], kr[B][KV][T][D], vT[B][KV][D][T] -> y[B][T][H*D] (bf16)
// grid = (T/64, B*H), 256 threads; wave w owns q-rows 16w..16w+15.
// ---------------------------------------------------------------------------
__global__ __launch_bounds__(256) void flash_k(
    const __bf16* __restrict__ qr, const __bf16* __restrict__ kr,
    const __bf16* __restrict__ vT, __bf16* __restrict__ y)
{
  const int qt  = blockIdx.x;           // 0..31
  const int bh  = blockIdx.y;           // 0..63
  const int b   = bh >> 5;
  const int h   = bh & 31;
  const int kvh = h >> 2;
  const int tq0 = qt * 64;
  const int tid  = threadIdx.x;
  const int lane = tid & 63;
  const int wave = tid >> 6;
  const int quad = lane >> 4;
  const int r    = lane & 15;

  __shared__ __bf16 q_sm[64 * 128];
  __shared__ __bf16 k_sm[64 * 128];
  __shared__ __bf16 v_sm[128 * 64];     // [d][t]
  __shared__ __bf16 p_sm[4 * 16 * 64];  // per-wave P staging (C-layout -> A-layout)

  const __bf16* qbase = qr + ((size_t)(b * 32 + h)   * 2048 + tq0) * 128;
  const __bf16* kbase = kr + ((size_t)(b * 8 + kvh)  * 2048) * 128;
  const __bf16* vbase = vT + ((size_t)(b * 8 + kvh)  * 128) * 2048;

  {   // stage Q tile [64][128]
    const int rowQ = lane >> 4, chQ = (lane & 15) * 8;
#pragma unroll
    for (int i = 0; i < 4; i++) {
      const int li = wave * 4 + i;
      __builtin_amdgcn_global_load_lds(AS1CV(qbase + (size_t)(li * 4 + rowQ) * 128 + chQ),
                                       AS3V(q_sm + li * 512), 16, 0, 0);
    }
  }

  f32x4 Oacc[8] = {};
  float mstate[4], lstate[4];
#pragma unroll
  for (int g = 0; g < 4; g++) { mstate[g] = -1e30f; lstate[g] = 0.0f; }
  const float scale = 0.08838834764831845f;   // 1/sqrt(128)

  for (int jt = 0; jt <= qt; jt++) {
    __syncthreads();
    {   // stage K [64][128] and V^T [128][64] tiles
      const int rowK = lane >> 4, chK = (lane & 15) * 8;
      const int rowV = lane >> 3, chV = (lane & 7) * 8;
#pragma unroll
      for (int i = 0; i < 4; i++) {
        const int li = wave * 4 + i;
        __builtin_amdgcn_global_load_lds(AS1CV(kbase + (size_t)(jt * 64 + li * 4 + rowK) * 128 + chK),
                                         AS3V(k_sm + li * 512), 16, 0, 0);
        __builtin_amdgcn_global_load_lds(AS1CV(vbase + (size_t)(li * 8 + rowV) * 2048 + jt * 64 + chV),
                                         AS3V(v_sm + li * 512), 16, 0, 0);
      }
    }
    __syncthreads();

    // S = Q K^T  (wave's 16 q-rows x 64 kv-cols)
    f32x4 S[4] = {};
#pragma unroll
    for (int kk = 0; kk < 4; kk++) {
      bf16x8 aq = *(const bf16x8*)(q_sm + (wave * 16 + r) * 128 + kk * 32 + quad * 8);
#pragma unroll
      for (int ni = 0; ni < 4; ni++) {
        bf16x8 bk = *(const bf16x8*)(k_sm + (ni * 16 + r) * 128 + kk * 32 + quad * 8);
        S[ni] = __builtin_amdgcn_mfma_f32_16x16x32_bf16(aq, bk, S[ni], 0, 0, 0);
      }
    }

    // online softmax; row = quad*4+g (C-layout), col = ni*16+r
    const bool diag = (jt == qt);
    float sc[4][4];
#pragma unroll
    for (int ni = 0; ni < 4; ni++)
#pragma unroll
      for (int g = 0; g < 4; g++) {
        float v = S[ni][g] * scale;
        if (diag) {
          const int rowg = tq0 + wave * 16 + quad * 4 + g;
          const int colg = jt * 64 + ni * 16 + r;
          if (colg > rowg) v = -3.0e38f;
        }
        sc[ni][g] = v;
      }
    float tmax[4];
#pragma unroll
    for (int g = 0; g < 4; g++)
      tmax[g] = fmaxf(fmaxf(sc[0][g], sc[1][g]), fmaxf(sc[2][g], sc[3][g]));
#pragma unroll
    for (int off = 1; off < 16; off <<= 1)
#pragma unroll
      for (int g = 0; g < 4; g++)
        tmax[g] = fmaxf(tmax[g], __shfl_xor(tmax[g], off));

    float mnew[4], alpha[4], p[4][4], rsum[4];
#pragma unroll
    for (int g = 0; g < 4; g++) {
      mnew[g]  = fmaxf(mstate[g], tmax[g]);
      alpha[g] = __expf(mstate[g] - mnew[g]);
      mstate[g] = mnew[g];
    }
#pragma unroll
    for (int ni = 0; ni < 4; ni++)
#pragma unroll
      for (int g = 0; g < 4; g++)
        p[ni][g] = __expf(sc[ni][g] - mnew[g]);   // masked -> 0
#pragma unroll
    for (int g = 0; g < 4; g++)
      rsum[g] = (p[0][g] + p[1][g]) + (p[2][g] + p[3][g]);
#pragma unroll
    for (int off = 1; off < 16; off <<= 1)
#pragma unroll
      for (int g = 0; g < 4; g++)
        rsum[g] += __shfl_xor(rsum[g], off);
#pragma unroll
    for (int g = 0; g < 4; g++)
      lstate[g] = lstate[g] * alpha[g] + rsum[g];
#pragma unroll
    for (int dt = 0; dt < 8; dt++)
#pragma unroll
      for (int g = 0; g < 4; g++)
        Oacc[dt][g] *= alpha[g];

    // P: C-layout regs -> A-layout via LDS (own-wave region only)
#pragma unroll
    for (int ni = 0; ni < 4; ni++)
#pragma unroll
      for (int g = 0; g < 4; g++)
        p_sm[wave * 1024 + (quad * 4 + g) * 64 + ni * 16 + r] = (__bf16)p[ni][g];
    __syncthreads();

    // O += P V
#pragma unroll
    for (int kk = 0; kk < 2; kk++) {
      bf16x8 ap = *(const bf16x8*)(p_sm + wave * 1024 + r * 64 + kk * 32 + quad * 8);
#pragma unroll
      for (int dt = 0; dt < 8; dt++) {
        bf16x8 bv = *(const bf16x8*)(v_sm + (dt * 16 + r) * 64 + kk * 32 + quad * 8);
        Oacc[dt] = __builtin_amdgcn_mfma_f32_16x16x32_bf16(ap, bv, Oacc[dt], 0, 0, 0);
      }
    }
  }

  // epilogue: y[b][t][h*128 + d] = O / l
#pragma unroll
  for (int dt = 0; dt < 8; dt++)
#pragma unroll
    for (int g = 0; g < 4; g++) {
      const int row = tq0 + wave * 16 + quad * 4 + g;
      const float val = Oacc[dt][g] / lstate[g];
      y[((size_t)(b * 2048 + row)) * 4096 + h * 128 + dt * 16 + r] = (__bf16)val;
    }
}

// ---------------------------------------------------------------------------
extern "C" void kernel_launch(void* const* d_in, const int* in_sizes, int n_in,
                              void* d_out, int out_size, void* d_ws, size_t ws_size,
                              hipStream_t stream)
{
  const float* x  = (const float*)d_in[0];
  // d_in[1] = mask (pure causal triu -> analytic)
  const float* wq = (const float*)d_in[2];
  const float* wk = (const float*)d_in[3];
  const float* wv = (const float*)d_in[4];
  const float* wo = (const float*)d_in[5];
  float* out = (float*)d_out;

  __bf16* ws  = (__bf16*)d_ws;
  __bf16* xb  = ws;                         // [4096][4096]      16,777,216
  __bf16* wT  = xb  + (size_t)16777216;     // [6144][4096]      25,165,824
  __bf16* qkv = wT  + (size_t)25165824;     // [4096][6144]      25,165,824
  __bf16* qr  = qkv + (size_t)25165824;     // [2][32][2048][128] 16,777,216
  __bf16* kr  = qr  + (size_t)16777216;     // [2][8][2048][128]   4,194,304
  __bf16* vT  = kr  + (size_t)4194304;      // [2][8][128][2048]   4,194,304
  __bf16* y   = xb;                         // alias: xb dead after gemm1
  __bf16* woT = wT;                         // alias: wT dead after gemm1
  // total ws use: 92,274,688 elems = 176 MiB

  dim3 blk(256);
  convert_k<<<dim3(16384), blk, 0, stream>>>(x, xb, 16777216L);
  transpose_f32_bf16_k<<<dim3(64, 64), blk, 0, stream>>>(wq, wT,                     4096L, 4096L);
  transpose_f32_bf16_k<<<dim3(16, 64), blk, 0, stream>>>(wk, wT + (size_t)4096*4096, 1024L, 4096L);
  transpose_f32_bf16_k<<<dim3(16, 64), blk, 0, stream>>>(wv, wT + (size_t)5120*4096, 1024L, 4096L);
  // fused QKV projection
  gemm_bt<__bf16><<<dim3(48, 32), blk, 0, stream>>>(xb, wT, qkv, 4096, 6144, 4096);
  // wo transpose reuses wT region (only after gemm1 is done on-stream)
  transpose_f32_bf16_k<<<dim3(64, 64), blk, 0, stream>>>(wo, woT, 4096L, 4096L);
  // RoPE + relayout q,k
  rope_k<<<dim3(4096), blk, 0, stream>>>(qkv, qr, kr);
  // V: [B][T][KV*D] slice -> [B][KV][D][T]
  transpose_bf16_k<<<dim3(2, 32, 16), blk, 0, stream>>>(qkv + 5120, vT, 6144L, 2048L,
                                                        8, (long)2048 * 6144, 128L, (long)128 * 2048);
  // flash attention
  flash_k<<<dim3(32, 64), blk, 0, stream>>>(qr, kr, vT, y);
  // output projection (fp32 out)
  gemm_bt<float><<<dim3(32, 32), blk, 0, stream>>>(y, woT, out, 4096, 4096, 4096);
}

// Round 3
// 912.310 us; speedup vs baseline: 1.4858x; 1.4858x over previous
//
#include <hip/hip_runtime.h>
#include <cstdint>
#include <cstddef>

typedef float  f32x4  __attribute__((ext_vector_type(4)));
typedef __bf16 bf16x8 __attribute__((ext_vector_type(8)));
typedef __bf16 bf16x4 __attribute__((ext_vector_type(4)));

// LDS aperture: low 32 bits of a flat shared pointer are the LDS offset.
#define AS1CV(p) ((const __attribute__((address_space(1))) void*)(uintptr_t)(p))
#define AS3V(p)  ((__attribute__((address_space(3))) void*)(uintptr_t)(p))
// wave-private LDS round-trip ordering (no cross-wave dependency -> no barrier)
#define LGKM0()  asm volatile("s_waitcnt lgkmcnt(0)" ::: "memory")

// ---------------------------------------------------------------------------
// fp32 -> bf16 convert (x).
// ---------------------------------------------------------------------------
__global__ __launch_bounds__(256) void convert_k(
    const float* __restrict__ in, __bf16* __restrict__ out, long n)
{
  const long i = ((long)blockIdx.x * 256 + threadIdx.x) * 4;
  if (i + 3 < n) {
    float4 v = *(const float4*)(in + i);
    __bf16 e[4] = { (__bf16)v.x, (__bf16)v.y, (__bf16)v.z, (__bf16)v.w };
    *(uint2*)(out + i) = *(const uint2*)e;
  }
}

// ---------------------------------------------------------------------------
// Weight transpose + convert: out_bf16[c][r] = (bf16)in_f32[r][c].
// ---------------------------------------------------------------------------
__global__ __launch_bounds__(256) void transpose_f32_bf16_k(
    const float* __restrict__ in, __bf16* __restrict__ out, long inRow, long outRow)
{
  const long tr = (long)blockIdx.y * 64;
  const long tc = (long)blockIdx.x * 64;
  __shared__ float tile[64][65];
  const int tid = threadIdx.x;
  const int rr = tid >> 4, c4 = (tid & 15) * 4;
#pragma unroll
  for (int p = 0; p < 4; p++) {
    const int r = p * 16 + rr;
    float4 v = *(const float4*)(in + (tr + r) * inRow + tc + c4);
    tile[r][c4]     = v.x;
    tile[r][c4 + 1] = v.y;
    tile[r][c4 + 2] = v.z;
    tile[r][c4 + 3] = v.w;
  }
  __syncthreads();
#pragma unroll
  for (int p = 0; p < 2; p++) {
    const int u  = p * 256 + tid;
    const int oc = u >> 3, ch = (u & 7) * 8;
    unsigned short e[8];
#pragma unroll
    for (int j = 0; j < 8; j++) {
      __bf16 b = (__bf16)tile[ch + j][oc];
      e[j] = *(unsigned short*)&b;
    }
    *(uint4*)(out + (tc + oc) * outRow + tr + ch) = *(const uint4*)e;
  }
}

// ---------------------------------------------------------------------------
// bf16 transpose with slices (V relayout): out[c][r] = in[r][c].
// ---------------------------------------------------------------------------
__global__ __launch_bounds__(256) void transpose_bf16_k(
    const __bf16* __restrict__ in, __bf16* __restrict__ out,
    long inRow, long outRow,
    int sliceDiv, long sliceOuter, long sliceInner, long outSlice)
{
  const int s = blockIdx.z;
  const __bf16* ip = in + (long)(s / sliceDiv) * sliceOuter + (long)(s % sliceDiv) * sliceInner;
  __bf16* op = out + (long)s * outSlice;
  const long tr = (long)blockIdx.y * 64;
  const long tc = (long)blockIdx.x * 64;
  __shared__ unsigned short tile[64][66];
  const int tid = threadIdx.x;
  const int rr  = tid >> 3;
  const int c8  = (tid & 7) * 8;
#pragma unroll
  for (int p = 0; p < 2; p++) {
    const int r = p * 32 + rr;
    uint4 v = *(const uint4*)(ip + (tr + r) * inRow + tc + c8);
    const unsigned short* e = (const unsigned short*)&v;
#pragma unroll
    for (int j = 0; j < 8; j++) tile[r][c8 + j] = e[j];
  }
  __syncthreads();
#pragma unroll
  for (int p = 0; p < 2; p++) {
    const int c = p * 32 + rr;
    unsigned short e[8];
#pragma unroll
    for (int j = 0; j < 8; j++) e[j] = tile[c8 + j][c];
    *(uint4*)(op + (tc + c) * outRow + tr + c8) = *(const uint4*)e;
  }
}

// ---------------------------------------------------------------------------
// GEMM: C[M][N] = A[M][K] * BT[N][K]^T, bf16 in, fp32 accum, OutT out.
// 128x128 tile, BK=64, XOR-swizzled LDS (conflict-free reads), 256 threads.
// ---------------------------------------------------------------------------
template <typename OutT>
__global__ __launch_bounds__(256) void gemm_bt(
    const __bf16* __restrict__ A, const __bf16* __restrict__ BT,
    OutT* __restrict__ C, int M, int N, int K)
{
  const int n0   = blockIdx.x * 128;
  const int m0   = blockIdx.y * 128;
  const int tid  = threadIdx.x;
  const int lane = tid & 63;
  const int wave = tid >> 6;
  const int quad = lane >> 4;
  const int r    = lane & 15;
  const int wm   = wave >> 1, wn = wave & 1;
  __shared__ __bf16 a_sm[128 * 64];   // [row][chunk^ (row&7)] chunks of 8
  __shared__ __bf16 b_sm[128 * 64];
  f32x4 acc[4][4] = {};
  const int rowLd = lane >> 3;        // 8 rows per wave-inst
  const int cLd   = lane & 7;         // 8 chunks per 128B row
  for (int k0 = 0; k0 < K; k0 += 64) {
    __syncthreads();
#pragma unroll
    for (int i = 0; i < 4; i++) {
      const int li  = wave * 4 + i;               // 16 insts cover 128 rows
      const int row = li * 8 + rowLd;
      const int sc  = (cLd ^ (row & 7)) * 8;      // swizzled source chunk
      __builtin_amdgcn_global_load_lds(AS1CV(A  + (size_t)(m0 + row) * K + k0 + sc),
                                       AS3V(a_sm + li * 512), 16, 0, 0);
      __builtin_amdgcn_global_load_lds(AS1CV(BT + (size_t)(n0 + row) * K + k0 + sc),
                                       AS3V(b_sm + li * 512), 16, 0, 0);
    }
    __syncthreads();
#pragma unroll
    for (int kk = 0; kk < 2; kk++) {
      bf16x8 af[4], bfr[4];
#pragma unroll
      for (int mi = 0; mi < 4; mi++)
        af[mi] = *(const bf16x8*)(a_sm + (wm * 64 + mi * 16 + r) * 64 +
                                  (((kk * 4 + quad) ^ (r & 7)) * 8));
#pragma unroll
      for (int ni = 0; ni < 4; ni++)
        bfr[ni] = *(const bf16x8*)(b_sm + (wn * 64 + ni * 16 + r) * 64 +
                                   (((kk * 4 + quad) ^ (r & 7)) * 8));
#pragma unroll
      for (int mi = 0; mi < 4; mi++)
#pragma unroll
        for (int ni = 0; ni < 4; ni++)
          acc[mi][ni] = __builtin_amdgcn_mfma_f32_16x16x32_bf16(af[mi], bfr[ni], acc[mi][ni], 0, 0, 0);
    }
  }
  // C/D layout: col = lane&15, row = quad*4 + reg
#pragma unroll
  for (int mi = 0; mi < 4; mi++)
#pragma unroll
    for (int ni = 0; ni < 4; ni++) {
      const int col = n0 + wn * 64 + ni * 16 + r;
#pragma unroll
      for (int g = 0; g < 4; g++) {
        const int row = m0 + wm * 64 + mi * 16 + quad * 4 + g;
        C[(size_t)row * N + col] = (OutT)acc[mi][ni][g];
      }
    }
}

// ---------------------------------------------------------------------------
// RoPE + relayout: qkv[B*T][6144](bf16) -> qr[B][H][T][D], kr[B][KV][T][D]
// ---------------------------------------------------------------------------
__global__ __launch_bounds__(256) void rope_k(
    const __bf16* __restrict__ qkv, __bf16* __restrict__ qr, __bf16* __restrict__ kr)
{
  const int m = blockIdx.x;
  const int b = m >> 11;
  const int t = m & 2047;
  const __bf16* rowp = qkv + (size_t)m * 6144;
  for (int n = threadIdx.x; n < 5120; n += 256) {
    const bool isq  = n < 4096;
    const int local = isq ? n : (n - 4096);
    const int head  = local >> 7;
    const int d     = local & 127;
    const int j     = d & 63;
    const float ex   = (float)(2 * j) / 128.0f;
    const float invf = 1.0f / powf(10000.0f, ex);
    const float ang  = ((float)t * invf) * 2.0f;   // * B=2 per reference quirk
    const float c = cosf(ang), s = sinf(ang);
    const float v0 = (float)rowp[n];
    const float v1 = (float)rowp[n + ((d < 64) ? 64 : -64)];
    const float o  = (d < 64) ? (v0 * c - v1 * s) : (v0 * c + v1 * s);
    if (isq) qr[((size_t)(b * 32 + head) * 2048 + t) * 128 + d] = (__bf16)o;
    else     kr[((size_t)(b * 8  + head) * 2048 + t) * 128 + d] = (__bf16)o;
  }
}

// ---------------------------------------------------------------------------
// Flash attention v2: S^T orientation, Q in registers, XOR-swizzled LDS,
// 2 barriers/iter, longest-first block order.
// qr[B][H][T][D], kr[B][KV][T][D], vT[B][KV][D][T] -> y[B][T][H*D] (bf16)
// grid = (T/64, B*H); wave w owns q-rows [16w,16w+16).
// ---------------------------------------------------------------------------
__global__ __launch_bounds__(256, 3) void flash_k(
    const __bf16* __restrict__ qr, const __bf16* __restrict__ kr,
    const __bf16* __restrict__ vT, __bf16* __restrict__ y)
{
  const int qt  = (int)gridDim.x - 1 - (int)blockIdx.x;  // longest blocks first
  const int bh  = blockIdx.y;
  const int b   = bh >> 5;
  const int h   = bh & 31;
  const int kvh = h >> 2;
  const int tq0 = qt * 64;
  const int tid  = threadIdx.x;
  const int lane = tid & 63;
  const int wave = tid >> 6;
  const int quad = lane >> 4;
  const int r    = lane & 15;

  __shared__ __bf16 k_sm[64 * 128];     // [kv][d], chunk^=(row&15)
  __shared__ __bf16 v_sm[128 * 64];     // [d][t],  chunk^=(row&7)
  __shared__ __bf16 p_sm[4][16 * 64];   // per-wave [q][kv], chunk^=(q&7)
  __shared__ float  al_sm[64];
  __shared__ float  l_sm[64];

  const __bf16* kbase = kr + ((size_t)(b * 8 + kvh) * 2048) * 128;
  const __bf16* vbase = vT + ((size_t)(b * 8 + kvh) * 128) * 2048;

  // Q fragments in registers (B-operand layout): Q[q=wave*16+r][kk*32+quad*8+j]
  bf16x8 qf[4];
  {
    const __bf16* qrow = qr + ((size_t)(b * 32 + h) * 2048 + tq0 + wave * 16 + r) * 128;
#pragma unroll
    for (int kk = 0; kk < 4; kk++)
      qf[kk] = *(const bf16x8*)(qrow + kk * 32 + quad * 8);
  }

  f32x4 Oacc[8] = {};
  float mstate = -1e30f, lstate = 0.0f;
  const float scale = 0.08838834764831845f;   // 1/sqrt(128)

  const int rowK = lane >> 4, cK = lane & 15;   // K staging: 4 rows x 16 chunks
  const int rowV = lane >> 3, cV = lane & 7;    // V staging: 8 rows x 8 chunks

  for (int jt = 0; jt <= qt; jt++) {
    __syncthreads();   // prev iter's k/v reads complete
#pragma unroll
    for (int i = 0; i < 4; i++) {
      const int li = wave * 4 + i;
      {
        const int row = li * 4 + rowK;
        const __bf16* g = kbase + (size_t)(jt * 64 + row) * 128 + ((cK ^ (row & 15)) * 8);
        __builtin_amdgcn_global_load_lds(AS1CV(g), AS3V(k_sm + li * 512), 16, 0, 0);
      }
      {
        const int row = li * 8 + rowV;
        const __bf16* g = vbase + (size_t)row * 2048 + jt * 64 + ((cV ^ (row & 7)) * 8);
        __builtin_amdgcn_global_load_lds(AS1CV(g), AS3V(v_sm + li * 512), 16, 0, 0);
      }
    }
    __syncthreads();   // staging visible

    // S^T = K·Q^T : lane holds S[kv=mi*16+quad*4+g][q=wave*16+r]
    f32x4 St[4] = {};
#pragma unroll
    for (int kk = 0; kk < 4; kk++)
#pragma unroll
      for (int mi = 0; mi < 4; mi++) {
        bf16x8 kf = *(const bf16x8*)(k_sm + (mi * 16 + r) * 128 + (((kk * 4 + quad) ^ r) * 8));
        St[mi] = __builtin_amdgcn_mfma_f32_16x16x32_bf16(kf, qf[kk], St[mi], 0, 0, 0);
      }

    // online softmax: full row (64 kv) = 16 in-lane values + 4 quads
    const bool diag = (jt == qt);
    const int qabs  = tq0 + wave * 16 + r;
    float p[16];
#pragma unroll
    for (int mi = 0; mi < 4; mi++)
#pragma unroll
      for (int g = 0; g < 4; g++) {
        float v = St[mi][g] * scale;
        if (diag && (jt * 64 + mi * 16 + quad * 4 + g) > qabs) v = -3.0e38f;
        p[mi * 4 + g] = v;
      }
    float mx = p[0];
#pragma unroll
    for (int i = 1; i < 16; i++) mx = fmaxf(mx, p[i]);
    mx = fmaxf(mx, __shfl_xor(mx, 16));
    mx = fmaxf(mx, __shfl_xor(mx, 32));
    const float mnew  = fmaxf(mstate, mx);
    const float alpha = __expf(mstate - mnew);
    mstate = mnew;
    float rs = 0.0f;
#pragma unroll
    for (int i = 0; i < 16; i++) { p[i] = __expf(p[i] - mnew); rs += p[i]; }
    rs += __shfl_xor(rs, 16);
    rs += __shfl_xor(rs, 32);
    lstate = lstate * alpha + rs;
    if (quad == 0) al_sm[wave * 16 + r] = alpha;

    // P -> p_sm (swizzled [q][kv]): kv = mi*16+quad*4+g, chunk cw = mi*2+(quad>>1)
#pragma unroll
    for (int mi = 0; mi < 4; mi++) {
      bf16x4 pk = { (__bf16)p[mi*4+0], (__bf16)p[mi*4+1], (__bf16)p[mi*4+2], (__bf16)p[mi*4+3] };
      const int cw = mi * 2 + (quad >> 1);
      *(bf16x4*)(&p_sm[wave][r * 64 + ((cw ^ (r & 7)) * 8) + (quad & 1) * 4]) = pk;
    }
    LGKM0();   // wave-private LDS ordering (write -> read below)

    // O rescale by alpha of q-rows quad*4+g (LDS broadcast reads)
    {
      const float a0 = al_sm[wave * 16 + quad * 4 + 0];
      const float a1 = al_sm[wave * 16 + quad * 4 + 1];
      const float a2 = al_sm[wave * 16 + quad * 4 + 2];
      const float a3 = al_sm[wave * 16 + quad * 4 + 3];
#pragma unroll
      for (int dt = 0; dt < 8; dt++) {
        Oacc[dt][0] *= a0; Oacc[dt][1] *= a1; Oacc[dt][2] *= a2; Oacc[dt][3] *= a3;
      }
    }

    // O += P·V  (A = P[q][kv] from p_sm, B = V^T[d][kv] from v_sm)
#pragma unroll
    for (int kk = 0; kk < 2; kk++) {
      bf16x8 pf = *(const bf16x8*)(&p_sm[wave][r * 64 + (((kk * 4 + quad) ^ (r & 7)) * 8)]);
#pragma unroll
      for (int dt = 0; dt < 8; dt++) {
        bf16x8 vf = *(const bf16x8*)(v_sm + (dt * 16 + r) * 64 + (((kk * 4 + quad) ^ (r & 7)) * 8));
        Oacc[dt] = __builtin_amdgcn_mfma_f32_16x16x32_bf16(pf, vf, Oacc[dt], 0, 0, 0);
      }
    }
  }

  if (quad == 0) l_sm[wave * 16 + r] = lstate;
  LGKM0();
  const float il0 = 1.0f / l_sm[wave * 16 + quad * 4 + 0];
  const float il1 = 1.0f / l_sm[wave * 16 + quad * 4 + 1];
  const float il2 = 1.0f / l_sm[wave * 16 + quad * 4 + 2];
  const float il3 = 1.0f / l_sm[wave * 16 + quad * 4 + 3];
#pragma unroll
  for (int dt = 0; dt < 8; dt++) {
    const int col = h * 128 + dt * 16 + r;
    const int row = tq0 + wave * 16 + quad * 4;
    y[((size_t)(b * 2048 + row + 0)) * 4096 + col] = (__bf16)(Oacc[dt][0] * il0);
    y[((size_t)(b * 2048 + row + 1)) * 4096 + col] = (__bf16)(Oacc[dt][1] * il1);
    y[((size_t)(b * 2048 + row + 2)) * 4096 + col] = (__bf16)(Oacc[dt][2] * il2);
    y[((size_t)(b * 2048 + row + 3)) * 4096 + col] = (__bf16)(Oacc[dt][3] * il3);
  }
}

// ---------------------------------------------------------------------------
extern "C" void kernel_launch(void* const* d_in, const int* in_sizes, int n_in,
                              void* d_out, int out_size, void* d_ws, size_t ws_size,
                              hipStream_t stream)
{
  const float* x  = (const float*)d_in[0];
  // d_in[1] = mask (pure causal triu -> analytic)
  const float* wq = (const float*)d_in[2];
  const float* wk = (const float*)d_in[3];
  const float* wv = (const float*)d_in[4];
  const float* wo = (const float*)d_in[5];
  float* out = (float*)d_out;

  __bf16* ws  = (__bf16*)d_ws;
  __bf16* xb  = ws;                         // [4096][4096]
  __bf16* wT  = xb  + (size_t)16777216;     // [6144][4096]
  __bf16* qkv = wT  + (size_t)25165824;     // [4096][6144]
  __bf16* qr  = qkv + (size_t)25165824;     // [2][32][2048][128]
  __bf16* kr  = qr  + (size_t)16777216;     // [2][8][2048][128]
  __bf16* vT  = kr  + (size_t)4194304;      // [2][8][128][2048]
  __bf16* y   = xb;                         // alias: xb dead after gemm1
  __bf16* woT = wT;                         // alias: wT dead after gemm1

  dim3 blk(256);
  convert_k<<<dim3(16384), blk, 0, stream>>>(x, xb, 16777216L);
  transpose_f32_bf16_k<<<dim3(64, 64), blk, 0, stream>>>(wq, wT,                     4096L, 4096L);
  transpose_f32_bf16_k<<<dim3(16, 64), blk, 0, stream>>>(wk, wT + (size_t)4096*4096, 1024L, 4096L);
  transpose_f32_bf16_k<<<dim3(16, 64), blk, 0, stream>>>(wv, wT + (size_t)5120*4096, 1024L, 4096L);
  gemm_bt<__bf16><<<dim3(48, 32), blk, 0, stream>>>(xb, wT, qkv, 4096, 6144, 4096);
  transpose_f32_bf16_k<<<dim3(64, 64), blk, 0, stream>>>(wo, woT, 4096L, 4096L);
  rope_k<<<dim3(4096), blk, 0, stream>>>(qkv, qr, kr);
  transpose_bf16_k<<<dim3(2, 32, 16), blk, 0, stream>>>(qkv + 5120, vT, 6144L, 2048L,
                                                        8, (long)2048 * 6144, 128L, (long)128 * 2048);
  flash_k<<<dim3(32, 64), blk, 0, stream>>>(qr, kr, vT, y);
  gemm_bt<float><<<dim3(32, 32), blk, 0, stream>>>(y, woT, out, 4096, 4096, 4096);
}